// Round 1
// baseline (654.549 us; speedup 1.0000x reference)
//
#include <hip/hip_runtime.h>
#include <hip/hip_bf16.h>

typedef __bf16 bf16_t;
typedef __attribute__((ext_vector_type(8))) __bf16 bf16x8;
typedef __attribute__((ext_vector_type(4))) __bf16 bf16x4;
typedef __attribute__((ext_vector_type(4))) float f32x4;

#define B_ 2
#define S_ 2048
#define D_ 7168
#define R_ 1024
#define H_ 16
#define VD_ 128
#define MROWS 4096   // B_*S_
#define NQKV 2048    // fused q|kv cols
#define HVD 2048     // H_*VD_

// ---------------- async global->LDS, 16B per lane ----------------
__device__ __forceinline__ void gload_lds16(const bf16_t* g, bf16_t* l) {
    __builtin_amdgcn_global_load_lds(
        (const __attribute__((address_space(1))) unsigned int*)(g),
        (__attribute__((address_space(3))) unsigned int*)(l),
        16, 0, 0);
}

// ---------------- f32 -> bf16 conversion (optionally scaled) ----------------
__global__ __launch_bounds__(256)
void cvt_f32_bf16(const float* __restrict__ src, bf16_t* __restrict__ dst, float scale) {
    size_t i = ((size_t)blockIdx.x * 256 + threadIdx.x) * 4;
    f32x4 v = *(const f32x4*)(src + i);
    bf16x4 o;
    o[0] = (bf16_t)(v[0] * scale);
    o[1] = (bf16_t)(v[1] * scale);
    o[2] = (bf16_t)(v[2] * scale);
    o[3] = (bf16_t)(v[3] * scale);
    *(bf16x4*)(dst + i) = o;
}

// ---------------- bf16 GEMM, C = A * Bt^T  (both K-major) ----------------
// A: [M][lda] bf16, Bt: [N][ldb] bf16, C: [M][ldc] (bf16 or f32+bias)
// 128x128 tile, BK=32, 4 waves (2x2 of 64x64), 16x16x32 MFMA. M,N,K % 128/32 == 0.
template<int OUTF32>
__global__ __launch_bounds__(256)
void gemm_bt(const bf16_t* __restrict__ A, int lda,
             const bf16_t* __restrict__ Bt, int ldb,
             void* __restrict__ Cv, int ldc,
             const float* __restrict__ bias, int K)
{
    __shared__ bf16_t As[128 * 32];
    __shared__ bf16_t Bs[128 * 32];
    const int tid  = threadIdx.x;
    const int lane = tid & 63;
    const int wave = tid >> 6;
    const int tileM = blockIdx.y * 128;
    const int tileN = blockIdx.x * 128;
    const int wr = (wave >> 1) * 64;
    const int wc = (wave & 1) * 64;
    const int r  = lane & 15;
    const int kq = lane >> 4;

    const bf16_t* Ag = A  + (size_t)tileM * lda;
    const bf16_t* Bg = Bt + (size_t)tileN * ldb;

    // staging: 2 issues x 256 threads x 16B cover 128x32 bf16
    const int lin0 = tid * 8;
    const int lin1 = (256 + tid) * 8;
    const int ar0 = lin0 >> 5, ac0 = lin0 & 31;
    const int ar1 = lin1 >> 5, ac1 = lin1 & 31;

    f32x4 acc[4][4] = {};

    for (int k0 = 0; k0 < K; k0 += 32) {
        gload_lds16(Ag + (size_t)ar0 * lda + k0 + ac0, As + lin0);
        gload_lds16(Ag + (size_t)ar1 * lda + k0 + ac1, As + lin1);
        gload_lds16(Bg + (size_t)ar0 * ldb + k0 + ac0, Bs + lin0);
        gload_lds16(Bg + (size_t)ar1 * ldb + k0 + ac1, Bs + lin1);
        __syncthreads();   // drains vmcnt -> LDS tiles ready

        bf16x8 af[4], bfr[4];
        #pragma unroll
        for (int m = 0; m < 4; ++m)
            af[m] = *(const bf16x8*)(As + (wr + m * 16 + r) * 32 + kq * 8);
        #pragma unroll
        for (int n = 0; n < 4; ++n)
            bfr[n] = *(const bf16x8*)(Bs + (wc + n * 16 + r) * 32 + kq * 8);
        #pragma unroll
        for (int m = 0; m < 4; ++m)
            #pragma unroll
            for (int n = 0; n < 4; ++n)
                acc[m][n] = __builtin_amdgcn_mfma_f32_16x16x32_bf16(af[m], bfr[n], acc[m][n], 0, 0, 0);
        __syncthreads();
    }

    // epilogue: D row=(lane>>4)*4+reg, col=lane&15
    const int orow = tileM + wr + kq * 4;
    const int ocol = tileN + wc + r;
    if (OUTF32) {
        float* C = (float*)Cv;
        #pragma unroll
        for (int n = 0; n < 4; ++n) {
            float bv = bias[ocol + n * 16];
            #pragma unroll
            for (int m = 0; m < 4; ++m)
                #pragma unroll
                for (int j = 0; j < 4; ++j)
                    C[(size_t)(orow + m * 16 + j) * ldc + ocol + n * 16] = acc[m][n][j] + bv;
        }
    } else {
        bf16_t* C = (bf16_t*)Cv;
        #pragma unroll
        for (int m = 0; m < 4; ++m)
            #pragma unroll
            for (int n = 0; n < 4; ++n)
                #pragma unroll
                for (int j = 0; j < 4; ++j)
                    C[(size_t)(orow + m * 16 + j) * ldc + ocol + n * 16] = (bf16_t)acc[m][n][j];
    }
}

// ---------------- causal flash attention in latent head space ----------------
// qkv: [4096][2048] bf16 (cols 0..1023 q_lat*1/SCALE, 1024..2047 kv_lat)
// Vt:  [2048][4096] bf16, row n=h*128+vd, col m=b*2048+s
// O:   [4096][2048] bf16 (attn output, [b,s][h*128+vd])
// 1 wave per block; 32 q-rows per block; KV tiles of 64.
__global__ __launch_bounds__(64)
void attn_kernel(const bf16_t* __restrict__ qkv, const bf16_t* __restrict__ Vt,
                 bf16_t* __restrict__ O)
{
    __shared__ bf16_t P_lds[32 * 64];
    const int lane = threadIdx.x;
    const int r  = lane & 15;
    const int kq = lane >> 4;
    const int qt = blockIdx.x;
    const int h  = blockIdx.y;
    const int b  = blockIdx.z;
    const int qbase = qt * 32;

    const bf16_t* Q  = qkv + (size_t)(b * S_) * NQKV + h * 64;
    const bf16_t* Kp = qkv + (size_t)(b * S_) * NQKV + R_ + h * 64;
    const bf16_t* Vp = Vt + (size_t)(h * VD_) * MROWS + b * S_;

    // hoist Q fragments: rows qbase..qbase+31, K-dim 64 (2 k-steps)
    bf16x8 qf[2][2];
    #pragma unroll
    for (int m = 0; m < 2; ++m)
        #pragma unroll
        for (int kk = 0; kk < 2; ++kk)
            qf[m][kk] = *(const bf16x8*)(Q + (size_t)(qbase + m * 16 + r) * NQKV + kk * 32 + kq * 8);

    f32x4 o[2][8] = {};
    float mst[2][4], lst[2][4];
    #pragma unroll
    for (int m = 0; m < 2; ++m)
        #pragma unroll
        for (int j = 0; j < 4; ++j) { mst[m][j] = -INFINITY; lst[m][j] = 0.0f; }

    const int nfull  = qbase >> 6;               // tiles fully below diagonal
    const int ntiles = (qbase + 95) >> 6;        // tiles to process

    for (int t = 0; t < ntiles; ++t) {
        const int kvb = t * 64;
        // ---- scores: S = Q K^T (both K-major, gemm_bt pattern) ----
        f32x4 s[2][4] = {};
        #pragma unroll
        for (int n = 0; n < 4; ++n) {
            bf16x8 kf0 = *(const bf16x8*)(Kp + (size_t)(kvb + n * 16 + r) * NQKV + kq * 8);
            bf16x8 kf1 = *(const bf16x8*)(Kp + (size_t)(kvb + n * 16 + r) * NQKV + 32 + kq * 8);
            #pragma unroll
            for (int m = 0; m < 2; ++m) {
                s[m][n] = __builtin_amdgcn_mfma_f32_16x16x32_bf16(qf[m][0], kf0, s[m][n], 0, 0, 0);
                s[m][n] = __builtin_amdgcn_mfma_f32_16x16x32_bf16(qf[m][1], kf1, s[m][n], 0, 0, 0);
            }
        }
        // ---- causal mask on diagonal tiles ----
        if (t >= nfull) {
            #pragma unroll
            for (int m = 0; m < 2; ++m)
                #pragma unroll
                for (int n = 0; n < 4; ++n)
                    #pragma unroll
                    for (int j = 0; j < 4; ++j) {
                        int kc = kvb + n * 16 + r;
                        int qr = qbase + m * 16 + kq * 4 + j;
                        if (kc > qr) s[m][n][j] = -1e30f;
                    }
        }
        // ---- online softmax (row stats across the 16 lanes of each kq group) ----
        float p[2][4][4];
        #pragma unroll
        for (int m = 0; m < 2; ++m) {
            #pragma unroll
            for (int j = 0; j < 4; ++j) {
                float mx = fmaxf(fmaxf(s[m][0][j], s[m][1][j]), fmaxf(s[m][2][j], s[m][3][j]));
                #pragma unroll
                for (int d = 1; d < 16; d <<= 1) mx = fmaxf(mx, __shfl_xor(mx, d, 64));
                float mnew  = fmaxf(mst[m][j], mx);
                float alpha = __expf(mst[m][j] - mnew);
                float rs = 0.0f;
                #pragma unroll
                for (int n = 0; n < 4; ++n) {
                    float pv = __expf(s[m][n][j] - mnew);
                    p[m][n][j] = pv;
                    rs += pv;
                }
                #pragma unroll
                for (int d = 1; d < 16; d <<= 1) rs += __shfl_xor(rs, d, 64);
                lst[m][j] = lst[m][j] * alpha + rs;
                mst[m][j] = mnew;
                #pragma unroll
                for (int n = 0; n < 8; ++n) o[m][n][j] *= alpha;
            }
        }
        // ---- P (score layout) -> LDS -> A-fragment layout ----
        #pragma unroll
        for (int m = 0; m < 2; ++m)
            #pragma unroll
            for (int n = 0; n < 4; ++n)
                #pragma unroll
                for (int j = 0; j < 4; ++j)
                    P_lds[(m * 16 + kq * 4 + j) * 64 + n * 16 + r] = (bf16_t)p[m][n][j];
        __syncthreads();
        bf16x8 pf[2][2];
        #pragma unroll
        for (int m = 0; m < 2; ++m)
            #pragma unroll
            for (int kk = 0; kk < 2; ++kk)
                pf[m][kk] = *(const bf16x8*)(P_lds + (m * 16 + r) * 64 + kk * 32 + kq * 8);
        // ---- O += P V  (V read K-contiguous from Vt) ----
        #pragma unroll
        for (int n = 0; n < 8; ++n) {
            bf16x8 vf0 = *(const bf16x8*)(Vp + (size_t)(n * 16 + r) * MROWS + kvb + kq * 8);
            bf16x8 vf1 = *(const bf16x8*)(Vp + (size_t)(n * 16 + r) * MROWS + kvb + 32 + kq * 8);
            #pragma unroll
            for (int m = 0; m < 2; ++m) {
                o[m][n] = __builtin_amdgcn_mfma_f32_16x16x32_bf16(pf[m][0], vf0, o[m][n], 0, 0, 0);
                o[m][n] = __builtin_amdgcn_mfma_f32_16x16x32_bf16(pf[m][1], vf1, o[m][n], 0, 0, 0);
            }
        }
        __syncthreads();
    }

    // ---- finalize: O /= l, write bf16 ----
    bf16_t* Op = O + (size_t)(b * S_ + qbase) * HVD + h * VD_;
    #pragma unroll
    for (int m = 0; m < 2; ++m)
        #pragma unroll
        for (int j = 0; j < 4; ++j) {
            float inv = 1.0f / lst[m][j];
            int row = m * 16 + kq * 4 + j;
            #pragma unroll
            for (int n = 0; n < 8; ++n)
                Op[(size_t)row * HVD + n * 16 + r] = (bf16_t)(o[m][n][j] * inv);
        }
}

extern "C" void kernel_launch(void* const* d_in, const int* in_sizes, int n_in,
                              void* d_out, int out_size, void* d_ws, size_t ws_size,
                              hipStream_t stream) {
    const float* x   = (const float*)d_in[0];
    const float* Wq  = (const float*)d_in[1];
    const float* Wkv = (const float*)d_in[2];
    const float* Wvb = (const float*)d_in[3];
    const float* Wo  = (const float*)d_in[4];
    const float* bo  = (const float*)d_in[5];

    // scratch in d_out (dead before final GEMM writes it)
    char* oc = (char*)d_out;
    bf16_t* xb     = (bf16_t*)oc;                    // 4096*7168*2 = 58,720,256 B
    bf16_t* Wqkv_b = (bf16_t*)(oc + 58720256);       // 2048*7168*2 = 29,360,128 B
    // scratch in d_ws (83,886,080 B total)
    char* ws = (char*)d_ws;
    bf16_t* qkv_b  = (bf16_t*)ws;                    // 4096*2048*2 = 16,777,216
    bf16_t* Wvb_b  = (bf16_t*)(ws + 16777216);       // 2048*1024*2 =  4,194,304
    bf16_t* Vt_b   = (bf16_t*)(ws + 20971520);       // 2048*4096*2 = 16,777,216
    bf16_t* attn_b = (bf16_t*)(ws + 37748736);       // 4096*2048*2 = 16,777,216
    bf16_t* Wo_b   = (bf16_t*)(ws + 54525952);       // 7168*2048*2 = 29,360,128

    const float inv_scale = 0.047245559f;            // 1/sqrt(448)

    // conversions (n/1024 blocks, 4 floats/thread, all sizes divide exactly)
    cvt_f32_bf16<<<29360128 / 1024, 256, 0, stream>>>(x,   xb, 1.0f);
    cvt_f32_bf16<<< 7340032 / 1024, 256, 0, stream>>>(Wq,  Wqkv_b, inv_scale);
    cvt_f32_bf16<<< 7340032 / 1024, 256, 0, stream>>>(Wkv, Wqkv_b + 7340032, 1.0f);
    cvt_f32_bf16<<< 2097152 / 1024, 256, 0, stream>>>(Wvb, Wvb_b, 1.0f);
    cvt_f32_bf16<<<14680064 / 1024, 256, 0, stream>>>(Wo,  Wo_b, 1.0f);

    // GEMM1: qkv_lat[4096][2048] = x @ [Wq*s | Wkv]^T   (K=7168)
    gemm_bt<0><<<dim3(16, 32), 256, 0, stream>>>(xb, D_, Wqkv_b, D_, qkv_b, NQKV, nullptr, D_);
    // GEMM2: Vt[2048][4096] = Wvb @ kv_lat^T            (K=1024)
    gemm_bt<0><<<dim3(32, 16), 256, 0, stream>>>(Wvb_b, R_, qkv_b + R_, NQKV, Vt_b, MROWS, nullptr, R_);
    // attention -> attn_b[4096][2048]
    attn_kernel<<<dim3(S_ / 32, H_, B_), 64, 0, stream>>>(qkv_b, Vt_b, attn_b);
    // GEMM4: out[4096][7168] = attn @ Wo^T + bo         (K=2048)
    gemm_bt<1><<<dim3(56, 32), 256, 0, stream>>>(attn_b, HVD, Wo_b, HVD, d_out, D_, bo, HVD);
}